// Round 4
// baseline (142.164 us; speedup 1.0000x reference)
//
#include <hip/hip_runtime.h>
#include <stdint.h>

// Problem constants (match reference)
#define N_PRIORS 2097152
#define KTOP 512
#define NBINS 2048
#define K1BLK 2048               // k1 grid (256 threads, 1024 elems each)
#define SELCAP 2048
#define SSTASH 0.9915f           // stash pre-filter; expected ~800 >= 512 (10 sigma)
#define NSUPB 16                 // suppression blocks (each owns 32 rows)

// ws layout:
// +0      u32 nsel_g          (memset 0 pre-k1)
// +4      u32 done_g          (memset 0 pre-k1)
// +128    u32 rowany_g[16]
// +256    u64 keys_g[2048]    (16 KB)  compact candidate keys (k1-written)
// +16640  float4 bbs_g[2048]  (32 KB)  decoded pixel boxes (k1-written)
// +49408  u64 supW_g[512*8]   (32 KB)  suppression matrix
//
// k1 compacts candidates (key + bit-exact decoded box) via one device atomic
// counter. k2's phase 1 is then: contiguous key read -> slot-carrying sort ->
// boxes from a warm 32 KB region. No scattered cold reads in k2's critical path.

__device__ __forceinline__ uint64_t pack_key(float s, int idx) {
    // descending score, ascending index tie-break (== stable top_k)
    return ((uint64_t)__float_as_uint(s) << 32) | (uint32_t)(~idx);
}

__device__ __forceinline__ float score_of(float c0, float c1) {
    #pragma clang fp contract(off)
    float m  = fmaxf(c0, c1);
    float e0 = expf(c0 - m);
    float e1 = expf(c1 - m);
    return e1 / (e0 + e1);
}

__device__ __forceinline__ int bin_of(float s) {
    #pragma clang fp contract(off)
    int b = (int)((s - 0.9f) * 20480.0f);   // 2048 bins over (0.9, 1.0]
    return b > (NBINS - 1) ? (NBINS - 1) : b;
}

__device__ __forceinline__ uint64_t shfl_xor64(uint64_t x, int mask) {
    int lo = __shfl_xor((int)(uint32_t)x, mask, 64);
    int hi = __shfl_xor((int)(uint32_t)(x >> 32), mask, 64);
    return ((uint64_t)(uint32_t)hi << 32) | (uint32_t)lo;
}

// Emit one candidate: compact slot via device atomic; decode box with the
// EXACT instruction sequence the reference decode uses (fp contract off).
__device__ __forceinline__ void emit_cand(float s, int idx,
                                          const float4* __restrict__ loc,
                                          const float4* __restrict__ priors,
                                          uint64_t* __restrict__ keys_g,
                                          float4* __restrict__ bbs_g,
                                          uint32_t* __restrict__ nsel_g) {
    #pragma clang fp contract(off)
    uint32_t p = atomicAdd(nsel_g, 1u);     // device scope by default
    if (p < SELCAP) {
        keys_g[p] = pack_key(s, idx);
        float4 l  = loc[idx];
        float4 pr = priors[idx];
        float cx = pr.x + (l.x * 0.1f) * pr.z;
        float cy = pr.y + (l.y * 0.1f) * pr.w;
        float w  = pr.z * expf(l.z * 0.2f);
        float h  = pr.w * expf(l.w * 0.2f);
        float x1 = cx - w * 0.5f;
        float y1 = cy - h * 0.5f;
        float x2 = x1 + w;
        float y2 = y1 + h;
        x1 *= 2048.0f; y1 *= 2048.0f; x2 *= 2048.0f; y2 *= 2048.0f;
        bbs_g[p] = make_float4(x1, y1, x2, y2);
    }
}

// K1: stream conf once (full grid); candidates (s > SSTASH) compacted with
// decode done here (~800 total: atomics + scattered loads are noise at this
// parallelism).
__global__ void k1_stash(const float4* __restrict__ conf4,
                         const float4* __restrict__ loc,
                         const float4* __restrict__ priors,
                         uint64_t* __restrict__ keys_g,
                         float4* __restrict__ bbs_g,
                         uint32_t* __restrict__ nsel_g) {
    #pragma clang fp contract(off)
    int t = threadIdx.x;            // 256 threads
    int blk = blockIdx.x;           // 2048 blocks
    #pragma unroll
    for (int i = 0; i < 2; ++i) {
        int f4i = blk * 512 + t + 256 * i;
        float4 c = conf4[f4i];
        float s0 = score_of(c.x, c.y);
        float s1 = score_of(c.z, c.w);
        if (s0 > SSTASH) emit_cand(s0, f4i * 2,     loc, priors, keys_g, bbs_g, nsel_g);
        if (s1 > SSTASH) emit_cand(s1, f4i * 2 + 1, loc, priors, keys_g, bbs_g, nsel_g);
    }
}

// K2 (fused): 16 blocks x 1024 threads.
// Phase 1 (all blocks, redundant, bit-identical): contiguous key load ->
//   (exact fallback if needed) -> slot-carrying hybrid bitonic sort ->
//   top-512 boxes from bbs_g (or full decode on fallback) into LDS.
// Phase 2: block b computes suppression rows [b*32, b*32+32) -> supW_g.
// Phase 3: last-arriving block stages supW_g (agent-scope atomic loads),
//   greedy bitmask scan + epilogue.
__launch_bounds__(1024)
__global__ void k2_fused(const float4* __restrict__ loc,
                         const float4* __restrict__ priors,
                         const float4* __restrict__ conf4,
                         const uint32_t* __restrict__ nsel_g,
                         const uint64_t* __restrict__ keys_g,
                         const float4* __restrict__ bbs_g,
                         uint32_t* done_g,
                         uint32_t* rowany_g,
                         uint64_t* supW_g,
                         float* __restrict__ out) {
    #pragma clang fp contract(off)
    __shared__ uint64_t arena[4096];        // 32 KB: sel+slt (sort) then supW stage
    uint64_t* sel  = arena;                 // [0..2048) u64 keys
    uint32_t* slt  = (uint32_t*)(arena + 2048);  // [0..2048) u32 slots
    uint64_t* supW = arena;                 // tail phase only (sort dead)
    __shared__ uint32_t hist[NBINS];        // 8 KB (fallback only)
    __shared__ float4 bpk[KTOP];            // 8 KB pixel boxes
    __shared__ float  sar[KTOP], ssc[KTOP]; // 4 KB
    __shared__ uint64_t keepw0[8];          // valid bits (pre-NMS)
    __shared__ uint64_t keepw[8];           // final keep bits
    __shared__ uint32_t rowanyL[16];
    __shared__ uint32_t nselS, anyS, tailS;
    __shared__ int bmaxS;

    int tid = threadIdx.x;          // 1024 threads
    int lane = tid & 63, wv = tid >> 6;

    if (tid == 0) { anyS = 0u; bmaxS = 0; }

    // ---- phase 1: candidate acquisition ----
    uint32_t n = *nsel_g;                   // uniform broadcast load
    bool fb = (n < KTOP) || (n > SELCAP);   // too few / k1 overflow -> exact path

    if (!fb) {
        for (int t = tid; t < (int)n; t += 1024) {
            sel[t] = keys_g[t];
            slt[t] = (uint32_t)t;
        }
    } else {
        // ---- exact fallback: 2-pass histogram select over all of conf ----
        if (tid == 0) nselS = 0u;
        for (int b = tid; b < NBINS; b += 1024) hist[b] = 0u;
        __syncthreads();
        for (int f = tid; f < N_PRIORS / 2; f += 1024) {
            float4 c = conf4[f];
            float s0 = score_of(c.x, c.y);
            float s1 = score_of(c.z, c.w);
            if (s0 > 0.9f) atomicAdd(&hist[bin_of(s0)], 1u);
            if (s1 > 0.9f) atomicAdd(&hist[bin_of(s1)], 1u);
        }
        __syncthreads();
        for (int off = 1; off < NBINS; off <<= 1) {
            int b0 = tid, b1 = tid + 1024;
            uint32_t v0 = hist[b0] + ((b0 + off < NBINS) ? hist[b0 + off] : 0u);
            uint32_t v1 = hist[b1] + ((b1 + off < NBINS) ? hist[b1 + off] : 0u);
            __syncthreads();
            hist[b0] = v0; hist[b1] = v1;
            __syncthreads();
        }
        if (hist[tid] >= KTOP) atomicMax(&bmaxS, tid);
        if (hist[tid + 1024] >= KTOP) atomicMax(&bmaxS, tid + 1024);
        __syncthreads();
        int B = bmaxS;
        for (int f = tid; f < N_PRIORS / 2; f += 1024) {
            float4 c = conf4[f];
            float s0 = score_of(c.x, c.y);
            float s1 = score_of(c.z, c.w);
            if (s0 > 0.9f && bin_of(s0) >= B) {
                uint32_t p = atomicAdd(&nselS, 1u);
                if (p < SELCAP) sel[p] = pack_key(s0, 2 * f);
            }
            if (s1 > 0.9f && bin_of(s1) >= B) {
                uint32_t p = atomicAdd(&nselS, 1u);
                if (p < SELCAP) sel[p] = pack_key(s1, 2 * f + 1);
            }
        }
        __syncthreads();
        n = nselS; if (n > SELCAP) n = SELCAP;
    }
    __syncthreads();

    int P = KTOP; while (P < (int)n) P <<= 1;
    for (int t = tid; t < P; t += 1024)
        if (t >= (int)n) { sel[t] = 0ull; slt[t] = 0u; }
    __syncthreads();

    uint64_t v;       // thread tid's key  (valid for tid < min(P,1024))
    uint32_t sl;      // thread tid's slot (pairs with v through the sort)

    if (P <= 1024) {
        // ---- hybrid bitonic sort, descending (0-padding sinks) ----
        v  = (tid < P) ? sel[tid] : 0ull;
        sl = (tid < P) ? slt[tid] : 0u;
        for (int k = 2; k <= P; k <<= 1) {
            // cross-wave phases (stride >= 64): via LDS, 2 barriers each
            for (int j = k >> 1; j >= 64; j >>= 1) {
                if (tid < P) { sel[tid] = v; slt[tid] = sl; }
                __syncthreads();
                if (tid < P) {
                    uint64_t pv = sel[tid ^ j];
                    uint32_t ps = slt[tid ^ j];
                    bool wmax = (((tid & j) == 0) == ((tid & k) == 0));
                    bool take = wmax ? (pv > v) : (pv < v);
                    if (take) { v = pv; sl = ps; }
                }
                __syncthreads();
            }
            // intra-wave phases (stride <= 32): register shuffles, no barriers
            int j0 = (k >> 1) < 32 ? (k >> 1) : 32;
            for (int j = j0; j >= 1; j >>= 1) {
                uint64_t pv = shfl_xor64(v, j);
                uint32_t ps = (uint32_t)__shfl_xor((int)sl, j, 64);
                bool wmax = (((tid & j) == 0) == ((tid & k) == 0));
                bool take = wmax ? (pv > v) : (pv < v);
                v = take ? pv : v; sl = take ? ps : sl;
            }
        }
    } else {
        // ---- rare overflow path (n > 1024): LDS bitonic, paired swap ----
        for (int k = 2; k <= P; k <<= 1) {
            for (int j = k >> 1; j > 0; j >>= 1) {
                for (int t = tid; t < P; t += 1024) {
                    int ixj = t ^ j;
                    if (ixj > t) {
                        uint64_t a = sel[t], b = sel[ixj];
                        bool sw = ((t & k) == 0) ? (a < b) : (a > b);
                        if (sw) {
                            sel[t] = b; sel[ixj] = a;
                            uint32_t sa = slt[t]; slt[t] = slt[ixj]; slt[ixj] = sa;
                        }
                    }
                }
                __syncthreads();
            }
        }
        v  = (tid < KTOP) ? sel[tid] : 0ull;
        sl = (tid < KTOP) ? slt[tid] : 0u;
    }

    // ---- top-512 boxes into LDS; valid-bit ballot ----
    {
        uint64_t key = (tid < KTOP) ? v : 0ull;
        if (tid < KTOP) {
            float4 bb; float area, sc;
            if (key != 0ull) {
                sc = __uint_as_float((uint32_t)(key >> 32));
                if (!fb) {
                    bb = bbs_g[sl];     // k1-decoded, bit-exact
                } else {
                    int idx  = (int)(~(uint32_t)key);
                    float4 l = loc[idx];
                    float4 p = priors[idx];
                    float cx = p.x + (l.x * 0.1f) * p.z;
                    float cy = p.y + (l.y * 0.1f) * p.w;
                    float w  = p.z * expf(l.z * 0.2f);
                    float h  = p.w * expf(l.w * 0.2f);
                    float x1 = cx - w * 0.5f;
                    float y1 = cy - h * 0.5f;
                    float x2 = x1 + w;
                    float y2 = y1 + h;
                    x1 *= 2048.0f; y1 *= 2048.0f; x2 *= 2048.0f; y2 *= 2048.0f;
                    bb = make_float4(x1, y1, x2, y2);
                }
                area = (bb.z - bb.x + 1.0f) * (bb.w - bb.y + 1.0f);
            } else {
                bb = make_float4(0.f, 0.f, 0.f, 0.f); area = 1.f; sc = 0.f;
            }
            bpk[tid] = bb; sar[tid] = area; ssc[tid] = sc;
        }
        uint64_t vb = __ballot(key != 0ull);    // wave w covers cols 64w..64w+63
        if (lane == 0 && wv < 8) keepw0[wv] = vb;
    }
    __syncthreads();    // bpk/sar/ssc/keepw0 ready; sel/slt dead

    // ---- suppression rows for this block: 16 waves x 2 rows ----
    {
        float4 cb0 = bpk[lane +   0], cb1 = bpk[lane +  64];
        float4 cb2 = bpk[lane + 128], cb3 = bpk[lane + 192];
        float4 cb4 = bpk[lane + 256], cb5 = bpk[lane + 320];
        float4 cb6 = bpk[lane + 384], cb7 = bpk[lane + 448];
        // identical formula+inputs as decode -> bit-identical areas
        float ca0 = (cb0.z - cb0.x + 1.0f) * (cb0.w - cb0.y + 1.0f);
        float ca1 = (cb1.z - cb1.x + 1.0f) * (cb1.w - cb1.y + 1.0f);
        float ca2 = (cb2.z - cb2.x + 1.0f) * (cb2.w - cb2.y + 1.0f);
        float ca3 = (cb3.z - cb3.x + 1.0f) * (cb3.w - cb3.y + 1.0f);
        float ca4 = (cb4.z - cb4.x + 1.0f) * (cb4.w - cb4.y + 1.0f);
        float ca5 = (cb5.z - cb5.x + 1.0f) * (cb5.w - cb5.y + 1.0f);
        float ca6 = (cb6.z - cb6.x + 1.0f) * (cb6.w - cb6.y + 1.0f);
        float ca7 = (cb7.z - cb7.x + 1.0f) * (cb7.w - cb7.y + 1.0f);
        #define SUPC(c, CB, CA) do { \
            float xx1 = fmaxf(rb.x, CB.x); float yy1 = fmaxf(rb.y, CB.y); \
            float xx2 = fminf(rb.z, CB.z); float yy2 = fminf(rb.w, CB.w); \
            float ww = fmaxf(xx2 - xx1 + 1.0f, 0.0f); \
            float hh = fmaxf(yy2 - yy1 + 1.0f, 0.0f); \
            float inter = ww * hh; \
            float iou = inter / (ra + (CA) - inter); \
            uint64_t wrd = __ballot(iou > 0.4f && (64 * (c) + lane) > r); \
            if (lane == 0) supW_g[r * 8 + (c)] = wrd; \
            any |= wrd; } while (0)
        uint32_t mybits = 0u;
        int rbase = blockIdx.x * 32 + wv * 2;
        for (int rr = 0; rr < 2; ++rr) {
            int r = rbase + rr;
            float4 rb = bpk[r];     // wave-uniform broadcast
            float ra = sar[r];
            uint64_t any = 0ull;
            SUPC(0, cb0, ca0); SUPC(1, cb1, ca1); SUPC(2, cb2, ca2); SUPC(3, cb3, ca3);
            SUPC(4, cb4, ca4); SUPC(5, cb5, ca5); SUPC(6, cb6, ca6); SUPC(7, cb7, ca7);
            if (lane == 0 && any != 0ull) mybits |= 1u << (r & 31);
        }
        #undef SUPC
        if (lane == 0 && mybits != 0u) atomicOr(&anyS, mybits);
    }
    __syncthreads();    // all supW_g stores of this block drained

    // ---- arrival: release fence + device counter; last block is the tail ----
    if (tid == 0) {
        rowany_g[blockIdx.x] = anyS;    // rows b*32.. -> word b exactly
        __threadfence();                // order my block's global writes
        uint32_t old = atomicAdd(done_g, 1u);
        tailS = (old == (uint32_t)(NSUPB - 1)) ? 1u : 0u;
    }
    __syncthreads();
    if (tailS == 0u) return;

    // ---- tail block: stage supW/rowany coherently, greedy scan, epilogue ----
    __threadfence();    // acquire side
    for (int i = tid; i < KTOP * 8; i += 1024)
        supW[i] = __hip_atomic_load(&supW_g[i], __ATOMIC_RELAXED,
                                    __HIP_MEMORY_SCOPE_AGENT);
    if (tid < 16)
        rowanyL[tid] = __hip_atomic_load(&rowany_g[tid], __ATOMIC_RELAXED,
                                         __HIP_MEMORY_SCOPE_AGENT);
    __syncthreads();

    if (tid == 0) {
        #define RA64(c) (((uint64_t)rowanyL[2*(c)]) | (((uint64_t)rowanyL[2*(c)+1]) << 32))
        uint64_t kp0 = keepw0[0], kp1 = keepw0[1], kp2 = keepw0[2], kp3 = keepw0[3];
        uint64_t kp4 = keepw0[4], kp5 = keepw0[5], kp6 = keepw0[6], kp7 = keepw0[7];
        #define APPLYROW(i) do { const uint64_t* rp = supW + (size_t)(i) * 8; \
            kp0 &= ~rp[0]; kp1 &= ~rp[1]; kp2 &= ~rp[2]; kp3 &= ~rp[3]; \
            kp4 &= ~rp[4]; kp5 &= ~rp[5]; kp6 &= ~rp[6]; kp7 &= ~rp[7]; } while (0)
        #define CHUNK(c, KPC) do { uint64_t ra = RA64(c); uint64_t m = (KPC) & ra; \
            while (m) { int b = __builtin_ctzll(m); APPLYROW((c) * 64 + b); \
                uint64_t above = (b == 63) ? 0ull : (~0ull << (b + 1)); \
                m = (KPC) & ra & above; } } while (0)
        CHUNK(0, kp0); CHUNK(1, kp1); CHUNK(2, kp2); CHUNK(3, kp3);
        CHUNK(4, kp4); CHUNK(5, kp5); CHUNK(6, kp6); CHUNK(7, kp7);
        keepw[0] = kp0; keepw[1] = kp1; keepw[2] = kp2; keepw[3] = kp3;
        keepw[4] = kp4; keepw[5] = kp5; keepw[6] = kp6; keepw[7] = kp7;
        #undef CHUNK
        #undef APPLYROW
        #undef RA64
    }
    __syncthreads();

    // ---- epilogue: [512,5], boxes /2048 (exact pow2), zeros if suppressed ----
    if (tid < KTOP) {
        const float inv = 1.0f / 2048.0f;
        int kb = (int)((keepw[tid >> 6] >> (tid & 63)) & 1ull);
        float4 bb = bpk[tid];
        float* o = out + tid * 5;
        if (kb) {
            o[0] = bb.x * inv;
            o[1] = bb.y * inv;
            o[2] = bb.z * inv;
            o[3] = bb.w * inv;
            o[4] = ssc[tid];
        } else {
            o[0] = 0.f; o[1] = 0.f; o[2] = 0.f; o[3] = 0.f; o[4] = 0.f;
        }
    }
}

extern "C" void kernel_launch(void* const* d_in, const int* in_sizes, int n_in,
                              void* d_out, int out_size, void* d_ws, size_t ws_size,
                              hipStream_t stream) {
    const float* loc    = (const float*)d_in[0];   // [1,N,4]
    const float* conf   = (const float*)d_in[1];   // [1,N,2]
    const float* priors = (const float*)d_in[2];   // [N,4]
    float* out = (float*)d_out;                    // [512,5]

    uint8_t* ws = (uint8_t*)d_ws;
    uint32_t* nsel_g   = (uint32_t*)ws;              // +0
    uint32_t* done_g   = (uint32_t*)(ws + 4);        // +4
    uint32_t* rowany_g = (uint32_t*)(ws + 128);      // 64 B
    uint64_t* keys_g   = (uint64_t*)(ws + 256);      // 16 KB
    float4*   bbs_g    = (float4*)(ws + 16640);      // 32 KB (16B aligned)
    uint64_t* supW_g   = (uint64_t*)(ws + 49408);    // 32 KB

    // zero the two counters (graph-capturable memset node); everything else
    // is fully written by its producer before any consumer reads it.
    hipMemsetAsync(ws, 0, 8, stream);
    k1_stash<<<K1BLK, 256, 0, stream>>>((const float4*)conf,
                                        (const float4*)loc,
                                        (const float4*)priors,
                                        keys_g, bbs_g, nsel_g);
    k2_fused<<<NSUPB, 1024, 0, stream>>>((const float4*)loc, (const float4*)priors,
                                         (const float4*)conf, nsel_g, keys_g, bbs_g,
                                         done_g, rowany_g, supW_g, out);
}

// Round 5
// 139.981 us; speedup vs baseline: 1.0156x; 1.0156x over previous
//
#include <hip/hip_runtime.h>
#include <stdint.h>

// Problem constants (match reference)
#define N_PRIORS 2097152
#define KTOP 512
#define NBINS 2048
#define K1BLK 2048               // k1 grid (256 threads, 1024 elems each)
#define SCAP 32                  // stash slots per k1 block (mean 0.39, Poisson-safe)
#define SELCAP 2048
#define SSTASH 0.9915f           // stash pre-filter; expected ~800 >= 512 (10 sigma)
#define NSUPB 16                 // suppression blocks (each owns 32 rows)

// ws layout:
// +0        u32 blk_cnt[2048]          (8 KB)    per-block candidate counts
// +8192     u64 key_stash[2048*32]     (512 KB)  packed keys, per-block regions
// +532480   float4 box_stash[2048*32]  (1 MB)    decoded pixel boxes (k1-written)
// +1581056  u32 done_g                 (zeroed by k1 block 0 -- no memset dispatch)
// +1581120  u32 rowany_g[16]
// +1581184  u64 supW_g[512*8]          (32 KB)   suppression matrix
//
// k1: zero global atomics (LDS counter per block), decodes boxes in-place.
// k2: coalesced blk_cnt read -> batch LDS-atomic compaction -> independent
// (non-dependent) stash reads -> slot-carrying sort -> boxes from LDS.

__device__ __forceinline__ uint64_t pack_key(float s, int idx) {
    // descending score, ascending index tie-break (== stable top_k)
    return ((uint64_t)__float_as_uint(s) << 32) | (uint32_t)(~idx);
}

__device__ __forceinline__ float score_of(float c0, float c1) {
    #pragma clang fp contract(off)
    float m  = fmaxf(c0, c1);
    float e0 = expf(c0 - m);
    float e1 = expf(c1 - m);
    return e1 / (e0 + e1);
}

__device__ __forceinline__ int bin_of(float s) {
    #pragma clang fp contract(off)
    int b = (int)((s - 0.9f) * 20480.0f);   // 2048 bins over (0.9, 1.0]
    return b > (NBINS - 1) ? (NBINS - 1) : b;
}

__device__ __forceinline__ uint64_t shfl_xor64(uint64_t x, int mask) {
    int lo = __shfl_xor((int)(uint32_t)x, mask, 64);
    int hi = __shfl_xor((int)(uint32_t)(x >> 32), mask, 64);
    return ((uint64_t)(uint32_t)hi << 32) | (uint32_t)lo;
}

// Box decode with the EXACT reference op order (fp contract off everywhere).
__device__ __forceinline__ float4 decode_box(int idx,
                                             const float4* __restrict__ loc,
                                             const float4* __restrict__ priors) {
    #pragma clang fp contract(off)
    float4 l = loc[idx];
    float4 p = priors[idx];
    float cx = p.x + (l.x * 0.1f) * p.z;
    float cy = p.y + (l.y * 0.1f) * p.w;
    float w  = p.z * expf(l.z * 0.2f);
    float h  = p.w * expf(l.w * 0.2f);
    float x1 = cx - w * 0.5f;
    float y1 = cy - h * 0.5f;
    float x2 = x1 + w;
    float y2 = y1 + h;
    x1 *= 2048.0f; y1 *= 2048.0f; x2 *= 2048.0f; y2 *= 2048.0f;
    return make_float4(x1, y1, x2, y2);
}

// K1: stream conf once (full grid); stash s > SSTASH into per-block regions,
// decoding the box here. Zero global atomics; LDS counter only. Block 0
// zeroes done_g (safe: all k1 blocks complete before k2 starts).
__global__ void k1_stash(const float4* __restrict__ conf4,
                         const float4* __restrict__ loc,
                         const float4* __restrict__ priors,
                         uint32_t* __restrict__ blk_cnt,
                         uint64_t* __restrict__ key_stash,
                         float4* __restrict__ box_stash,
                         uint32_t* __restrict__ done_g) {
    #pragma clang fp contract(off)
    __shared__ uint32_t lcnt;
    int t = threadIdx.x;            // 256 threads
    int blk = blockIdx.x;           // 2048 blocks, 512 float4 (1024 elems) each
    if (blk == 0 && t == 0) *done_g = 0u;    // reset tail counter for k2
    if (t == 0) lcnt = 0;
    __syncthreads();
    uint64_t* kreg = key_stash + (size_t)blk * SCAP;
    float4*   breg = box_stash + (size_t)blk * SCAP;
    #pragma unroll
    for (int i = 0; i < 2; ++i) {
        int f4i = blk * 512 + t + 256 * i;
        float4 c = conf4[f4i];
        float s0 = score_of(c.x, c.y);
        float s1 = score_of(c.z, c.w);
        if (s0 > SSTASH) {
            uint32_t p = atomicAdd(&lcnt, 1u);
            if (p < SCAP) {
                kreg[p] = pack_key(s0, f4i * 2);
                breg[p] = decode_box(f4i * 2, loc, priors);
            }
        }
        if (s1 > SSTASH) {
            uint32_t p = atomicAdd(&lcnt, 1u);
            if (p < SCAP) {
                kreg[p] = pack_key(s1, f4i * 2 + 1);
                breg[p] = decode_box(f4i * 2 + 1, loc, priors);
            }
        }
    }
    __syncthreads();
    if (t == 0) blk_cnt[blk] = (lcnt <= SCAP) ? lcnt : 0xFFFFFFFFu;
}

// K2 (fused): 16 blocks x 1024 threads.
// Phase 1 (all blocks, redundant, bit-identical result: keys unique so the
//   sorted order is independent of compaction order): coalesced blk_cnt read
//   -> batch LDS-atomic compaction of keys+boxes into LDS -> (exact fallback
//   if needed) -> slot-carrying hybrid bitonic sort -> top-512 boxes from LDS.
// Phase 2: block b computes suppression rows [b*32, b*32+32) -> supW_g.
// Phase 3: last-arriving block stages supW_g (agent-scope atomic loads),
//   greedy bitmask scan + epilogue.
__launch_bounds__(1024)
__global__ void k2_fused(const float4* __restrict__ loc,
                         const float4* __restrict__ priors,
                         const float4* __restrict__ conf4,
                         const uint32_t* __restrict__ blk_cnt,
                         const uint64_t* __restrict__ key_stash,
                         const float4* __restrict__ box_stash,
                         uint32_t* done_g,
                         uint32_t* rowany_g,
                         uint64_t* supW_g,
                         float* __restrict__ out) {
    #pragma clang fp contract(off)
    __shared__ uint64_t arena[4096];        // 32 KB: sel+slt (sort) then supW stage
    uint64_t* sel  = arena;                 // [0..2048) u64 keys
    uint32_t* slt  = (uint32_t*)(arena + 2048);  // [0..2048) u32 slots
    uint64_t* supW = arena;                 // tail phase only (sort dead)
    __shared__ float4 bbxL[SELCAP];         // 32 KB compacted boxes (gather path)
    __shared__ uint32_t hist[NBINS];        // 8 KB (fallback only)
    __shared__ float4 bpk[KTOP];            // 8 KB pixel boxes
    __shared__ float  sar[KTOP], ssc[KTOP]; // 4 KB
    __shared__ uint64_t keepw0[8];          // valid bits (pre-NMS)
    __shared__ uint64_t keepw[8];           // final keep bits
    __shared__ uint32_t rowanyL[16];
    __shared__ uint32_t nselS, fbS, anyS, tailS;
    __shared__ int bmaxS;

    int tid = threadIdx.x;          // 1024 threads
    int lane = tid & 63, wv = tid >> 6;

    if (tid == 0) { nselS = 0u; fbS = 0u; anyS = 0u; bmaxS = 0; }
    __syncthreads();

    // ---- gather: coalesced counts, batch compaction, independent reads ----
    for (int b = tid; b < K1BLK; b += 1024) {
        uint32_t c = blk_cnt[b];
        if (c == 0xFFFFFFFFu) { atomicOr(&fbS, 1u); c = 0; }
        uint32_t base = 0;
        if (c > 0) base = atomicAdd(&nselS, c);
        for (uint32_t j = 0; j < c; ++j) {
            uint32_t p = base + j;
            if (p < SELCAP) {
                sel[p]  = key_stash[(size_t)b * SCAP + j];
                bbxL[p] = box_stash[(size_t)b * SCAP + j];
                slt[p]  = p;
            } else {
                atomicOr(&fbS, 1u);
            }
        }
    }
    __syncthreads();
    uint32_t n = nselS;
    bool fb = (fbS != 0u) || (n < KTOP) || (n > SELCAP);
    __syncthreads();

    if (fb) {
        // ---- exact fallback: 2-pass histogram select over all of conf ----
        if (tid == 0) nselS = 0u;
        for (int b = tid; b < NBINS; b += 1024) hist[b] = 0u;
        __syncthreads();
        for (int f = tid; f < N_PRIORS / 2; f += 1024) {
            float4 c = conf4[f];
            float s0 = score_of(c.x, c.y);
            float s1 = score_of(c.z, c.w);
            if (s0 > 0.9f) atomicAdd(&hist[bin_of(s0)], 1u);
            if (s1 > 0.9f) atomicAdd(&hist[bin_of(s1)], 1u);
        }
        __syncthreads();
        for (int off = 1; off < NBINS; off <<= 1) {
            int b0 = tid, b1 = tid + 1024;
            uint32_t v0 = hist[b0] + ((b0 + off < NBINS) ? hist[b0 + off] : 0u);
            uint32_t v1 = hist[b1] + ((b1 + off < NBINS) ? hist[b1 + off] : 0u);
            __syncthreads();
            hist[b0] = v0; hist[b1] = v1;
            __syncthreads();
        }
        if (hist[tid] >= KTOP) atomicMax(&bmaxS, tid);
        if (hist[tid + 1024] >= KTOP) atomicMax(&bmaxS, tid + 1024);
        __syncthreads();
        int B = bmaxS;
        for (int f = tid; f < N_PRIORS / 2; f += 1024) {
            float4 c = conf4[f];
            float s0 = score_of(c.x, c.y);
            float s1 = score_of(c.z, c.w);
            if (s0 > 0.9f && bin_of(s0) >= B) {
                uint32_t p = atomicAdd(&nselS, 1u);
                if (p < SELCAP) { sel[p] = pack_key(s0, 2 * f); slt[p] = p; }
            }
            if (s1 > 0.9f && bin_of(s1) >= B) {
                uint32_t p = atomicAdd(&nselS, 1u);
                if (p < SELCAP) { sel[p] = pack_key(s1, 2 * f + 1); slt[p] = p; }
            }
        }
        __syncthreads();
        n = nselS; if (n > SELCAP) n = SELCAP;
        __syncthreads();
    }

    int P = KTOP; while (P < (int)n) P <<= 1;
    for (int t = tid; t < P; t += 1024)
        if (t >= (int)n) { sel[t] = 0ull; slt[t] = 0u; }
    __syncthreads();

    uint64_t v;       // thread tid's key  (valid for tid < min(P,1024))
    uint32_t sl;      // thread tid's slot (pairs with v through the sort)

    if (P <= 1024) {
        // ---- hybrid bitonic sort, descending (0-padding sinks) ----
        v  = (tid < P) ? sel[tid] : 0ull;
        sl = (tid < P) ? slt[tid] : 0u;
        for (int k = 2; k <= P; k <<= 1) {
            // cross-wave phases (stride >= 64): via LDS, 2 barriers each
            for (int j = k >> 1; j >= 64; j >>= 1) {
                if (tid < P) { sel[tid] = v; slt[tid] = sl; }
                __syncthreads();
                if (tid < P) {
                    uint64_t pv = sel[tid ^ j];
                    uint32_t ps = slt[tid ^ j];
                    bool wmax = (((tid & j) == 0) == ((tid & k) == 0));
                    bool take = wmax ? (pv > v) : (pv < v);
                    if (take) { v = pv; sl = ps; }
                }
                __syncthreads();
            }
            // intra-wave phases (stride <= 32): register shuffles, no barriers
            int j0 = (k >> 1) < 32 ? (k >> 1) : 32;
            for (int j = j0; j >= 1; j >>= 1) {
                uint64_t pv = shfl_xor64(v, j);
                uint32_t ps = (uint32_t)__shfl_xor((int)sl, j, 64);
                bool wmax = (((tid & j) == 0) == ((tid & k) == 0));
                bool take = wmax ? (pv > v) : (pv < v);
                v = take ? pv : v; sl = take ? ps : sl;
            }
        }
    } else {
        // ---- rare overflow path (n > 1024): LDS bitonic, paired swap ----
        for (int k = 2; k <= P; k <<= 1) {
            for (int j = k >> 1; j > 0; j >>= 1) {
                for (int t = tid; t < P; t += 1024) {
                    int ixj = t ^ j;
                    if (ixj > t) {
                        uint64_t a = sel[t], b = sel[ixj];
                        bool sw = ((t & k) == 0) ? (a < b) : (a > b);
                        if (sw) {
                            sel[t] = b; sel[ixj] = a;
                            uint32_t sa = slt[t]; slt[t] = slt[ixj]; slt[ixj] = sa;
                        }
                    }
                }
                __syncthreads();
            }
        }
        v  = (tid < KTOP) ? sel[tid] : 0ull;
        sl = (tid < KTOP) ? slt[tid] : 0u;
    }

    // ---- top-512 boxes into LDS; valid-bit ballot ----
    {
        uint64_t key = (tid < KTOP) ? v : 0ull;
        if (tid < KTOP) {
            float4 bb; float area, sc;
            if (key != 0ull) {
                sc = __uint_as_float((uint32_t)(key >> 32));
                if (!fb) {
                    bb = bbxL[sl];      // k1-decoded, bit-exact, LDS-resident
                } else {
                    int idx = (int)(~(uint32_t)key);
                    bb = decode_box(idx, loc, priors);
                }
                area = (bb.z - bb.x + 1.0f) * (bb.w - bb.y + 1.0f);
            } else {
                bb = make_float4(0.f, 0.f, 0.f, 0.f); area = 1.f; sc = 0.f;
            }
            bpk[tid] = bb; sar[tid] = area; ssc[tid] = sc;
        }
        uint64_t vb = __ballot(key != 0ull);    // wave w covers cols 64w..64w+63
        if (lane == 0 && wv < 8) keepw0[wv] = vb;
    }
    __syncthreads();    // bpk/sar/ssc/keepw0 ready; sel/slt dead

    // ---- suppression rows for this block: 16 waves x 2 rows ----
    {
        float4 cb0 = bpk[lane +   0], cb1 = bpk[lane +  64];
        float4 cb2 = bpk[lane + 128], cb3 = bpk[lane + 192];
        float4 cb4 = bpk[lane + 256], cb5 = bpk[lane + 320];
        float4 cb6 = bpk[lane + 384], cb7 = bpk[lane + 448];
        // identical formula+inputs as decode -> bit-identical areas
        float ca0 = (cb0.z - cb0.x + 1.0f) * (cb0.w - cb0.y + 1.0f);
        float ca1 = (cb1.z - cb1.x + 1.0f) * (cb1.w - cb1.y + 1.0f);
        float ca2 = (cb2.z - cb2.x + 1.0f) * (cb2.w - cb2.y + 1.0f);
        float ca3 = (cb3.z - cb3.x + 1.0f) * (cb3.w - cb3.y + 1.0f);
        float ca4 = (cb4.z - cb4.x + 1.0f) * (cb4.w - cb4.y + 1.0f);
        float ca5 = (cb5.z - cb5.x + 1.0f) * (cb5.w - cb5.y + 1.0f);
        float ca6 = (cb6.z - cb6.x + 1.0f) * (cb6.w - cb6.y + 1.0f);
        float ca7 = (cb7.z - cb7.x + 1.0f) * (cb7.w - cb7.y + 1.0f);
        #define SUPC(c, CB, CA) do { \
            float xx1 = fmaxf(rb.x, CB.x); float yy1 = fmaxf(rb.y, CB.y); \
            float xx2 = fminf(rb.z, CB.z); float yy2 = fminf(rb.w, CB.w); \
            float ww = fmaxf(xx2 - xx1 + 1.0f, 0.0f); \
            float hh = fmaxf(yy2 - yy1 + 1.0f, 0.0f); \
            float inter = ww * hh; \
            float iou = inter / (ra + (CA) - inter); \
            uint64_t wrd = __ballot(iou > 0.4f && (64 * (c) + lane) > r); \
            if (lane == 0) supW_g[r * 8 + (c)] = wrd; \
            any |= wrd; } while (0)
        uint32_t mybits = 0u;
        int rbase = blockIdx.x * 32 + wv * 2;
        for (int rr = 0; rr < 2; ++rr) {
            int r = rbase + rr;
            float4 rb = bpk[r];     // wave-uniform broadcast
            float ra = sar[r];
            uint64_t any = 0ull;
            SUPC(0, cb0, ca0); SUPC(1, cb1, ca1); SUPC(2, cb2, ca2); SUPC(3, cb3, ca3);
            SUPC(4, cb4, ca4); SUPC(5, cb5, ca5); SUPC(6, cb6, ca6); SUPC(7, cb7, ca7);
            if (lane == 0 && any != 0ull) mybits |= 1u << (r & 31);
        }
        #undef SUPC
        if (lane == 0 && mybits != 0u) atomicOr(&anyS, mybits);
    }
    __syncthreads();    // all supW_g stores of this block drained

    // ---- arrival: release fence + device counter; last block is the tail ----
    if (tid == 0) {
        rowany_g[blockIdx.x] = anyS;    // rows b*32.. -> word b exactly
        __threadfence();                // order my block's global writes
        uint32_t old = atomicAdd(done_g, 1u);
        tailS = (old == (uint32_t)(NSUPB - 1)) ? 1u : 0u;
    }
    __syncthreads();
    if (tailS == 0u) return;

    // ---- tail block: stage supW/rowany coherently, greedy scan, epilogue ----
    __threadfence();    // acquire side
    for (int i = tid; i < KTOP * 8; i += 1024)
        supW[i] = __hip_atomic_load(&supW_g[i], __ATOMIC_RELAXED,
                                    __HIP_MEMORY_SCOPE_AGENT);
    if (tid < 16)
        rowanyL[tid] = __hip_atomic_load(&rowany_g[tid], __ATOMIC_RELAXED,
                                         __HIP_MEMORY_SCOPE_AGENT);
    __syncthreads();

    if (tid == 0) {
        #define RA64(c) (((uint64_t)rowanyL[2*(c)]) | (((uint64_t)rowanyL[2*(c)+1]) << 32))
        uint64_t kp0 = keepw0[0], kp1 = keepw0[1], kp2 = keepw0[2], kp3 = keepw0[3];
        uint64_t kp4 = keepw0[4], kp5 = keepw0[5], kp6 = keepw0[6], kp7 = keepw0[7];
        #define APPLYROW(i) do { const uint64_t* rp = supW + (size_t)(i) * 8; \
            kp0 &= ~rp[0]; kp1 &= ~rp[1]; kp2 &= ~rp[2]; kp3 &= ~rp[3]; \
            kp4 &= ~rp[4]; kp5 &= ~rp[5]; kp6 &= ~rp[6]; kp7 &= ~rp[7]; } while (0)
        #define CHUNK(c, KPC) do { uint64_t ra = RA64(c); uint64_t m = (KPC) & ra; \
            while (m) { int b = __builtin_ctzll(m); APPLYROW((c) * 64 + b); \
                uint64_t above = (b == 63) ? 0ull : (~0ull << (b + 1)); \
                m = (KPC) & ra & above; } } while (0)
        CHUNK(0, kp0); CHUNK(1, kp1); CHUNK(2, kp2); CHUNK(3, kp3);
        CHUNK(4, kp4); CHUNK(5, kp5); CHUNK(6, kp6); CHUNK(7, kp7);
        keepw[0] = kp0; keepw[1] = kp1; keepw[2] = kp2; keepw[3] = kp3;
        keepw[4] = kp4; keepw[5] = kp5; keepw[6] = kp6; keepw[7] = kp7;
        #undef CHUNK
        #undef APPLYROW
        #undef RA64
    }
    __syncthreads();

    // ---- epilogue: [512,5], boxes /2048 (exact pow2), zeros if suppressed ----
    if (tid < KTOP) {
        const float inv = 1.0f / 2048.0f;
        int kb = (int)((keepw[tid >> 6] >> (tid & 63)) & 1ull);
        float4 bb = bpk[tid];
        float* o = out + tid * 5;
        if (kb) {
            o[0] = bb.x * inv;
            o[1] = bb.y * inv;
            o[2] = bb.z * inv;
            o[3] = bb.w * inv;
            o[4] = ssc[tid];
        } else {
            o[0] = 0.f; o[1] = 0.f; o[2] = 0.f; o[3] = 0.f; o[4] = 0.f;
        }
    }
}

extern "C" void kernel_launch(void* const* d_in, const int* in_sizes, int n_in,
                              void* d_out, int out_size, void* d_ws, size_t ws_size,
                              hipStream_t stream) {
    const float* loc    = (const float*)d_in[0];   // [1,N,4]
    const float* conf   = (const float*)d_in[1];   // [1,N,2]
    const float* priors = (const float*)d_in[2];   // [N,4]
    float* out = (float*)d_out;                    // [512,5]

    uint8_t* ws = (uint8_t*)d_ws;
    uint32_t* blk_cnt   = (uint32_t*)ws;               // 8 KB
    uint64_t* key_stash = (uint64_t*)(ws + 8192);      // 512 KB (ends 532480)
    float4*   box_stash = (float4*)(ws + 532480);      // 1 MB  (ends 1581056)
    uint32_t* done_g    = (uint32_t*)(ws + 1581056);   // 4 B (zeroed by k1)
    uint32_t* rowany_g  = (uint32_t*)(ws + 1581120);   // 64 B
    uint64_t* supW_g    = (uint64_t*)(ws + 1581184);   // 32 KB

    // no memset needed: blk_cnt + done_g fully written by k1 before k2 reads;
    // supW_g/rowany_g fully written by k2 blocks before the tail reads them
    // (threadfence + device-scope atomic arrival, agent-scope staged loads).
    k1_stash<<<K1BLK, 256, 0, stream>>>((const float4*)conf,
                                        (const float4*)loc,
                                        (const float4*)priors,
                                        blk_cnt, key_stash, box_stash, done_g);
    k2_fused<<<NSUPB, 1024, 0, stream>>>((const float4*)loc, (const float4*)priors,
                                         (const float4*)conf, blk_cnt,
                                         key_stash, box_stash,
                                         done_g, rowany_g, supW_g, out);
}